// Round 2
// baseline (266.150 us; speedup 1.0000x reference)
//
#include <hip/hip_runtime.h>
#include <stdint.h>

namespace {
constexpr int N_   = 1024;
constexpr int BND_ = 4;
constexpr int WP_  = N_ + 2 * BND_;   // 1032
constexpr int NN_  = N_ * N_;         // 1<<20

// Direct-gather version: no LDS, no barrier. grid (64 MB) + vec (128 MB) +
// out (64 MB) are L3-resident; the 4 bilinear taps/pixel are L1/L2 hits with
// contiguous-lane locality, so LDS staging only added a vmcnt(0) barrier
// stall (VALUBusy was 18% with 3.9M LDS-conflict cycles). Here every wave
// streams independently: 32 tap loads of MLP per thread, full occupancy.
//
// Tile: 128x16 pixels per 256-thread block. Each thread owns 2 adjacent
// columns x 4 rows -> vec loads are float4 (16 B/lane, coalesced), out
// stores are float2 (8 B/lane, coalesced).
constexpr int TW_ = 128;
constexpr int TH_ = 16;
constexpr int TILES_X = N_ / TW_;              // 8
constexpr int TILES_PER_IMG = TILES_X * (N_ / TH_);  // 512

// Exact replication of reference gather (rare fallback, border pixels only):
// clip flat index into padded (WP x WP) sdf, then pad value 1.0 or interior
// grid value. Reproduces the reference's flat-index clip/wrap semantics.
__device__ __forceinline__ float fetch_pad(const float* __restrict__ gb, int idx) {
    idx = min(max(idx, 0), WP_ * WP_ - 1);
    int yy = idx / WP_;
    int xx = idx - yy * WP_;
    if (xx >= BND_ && xx < WP_ - BND_ && yy >= BND_ && yy < WP_ - BND_)
        return gb[(yy - BND_) * N_ + (xx - BND_)];
    return 1.0f;
}
} // namespace

__global__ __launch_bounds__(256, 6) void advect_kernel(
    const float* __restrict__ grid,   // (B,N,N) fp32
    const float* __restrict__ vec,    // (B,N,N,2) fp32
    float* __restrict__ out)          // (B,N,N) fp32
{
    int bid = blockIdx.x;
    int b   = bid >> 9;               // / TILES_PER_IMG (512)
    int t   = bid & 511;
    int tyi = t >> 3;                 // / TILES_X  (0..63)
    int txi = t & 7;
    int it  = txi * TW_;              // tile origin (pixel coords)
    int jt  = tyi * TH_;

    int tid = threadIdx.x;
    int cp  = tid & 63;               // column-pair index 0..63 (wave-contiguous)
    int rr  = tid >> 6;               // wave id 0..3 -> row offset
    int i0  = it + 2 * cp;            // this thread's first column

    const float* gb = grid + (size_t)b * NN_;

    // ---- Load this thread's 8 displacement vectors as 4 float4 ----
    // Wave lanes 0..63 read 64*16 B contiguous per instruction.
    float4 pv[4];
#pragma unroll
    for (int s = 0; s < 4; ++s) {
        int j = jt + rr + 4 * s;
        pv[s] = *reinterpret_cast<const float4*>(
            vec + 2 * ((size_t)b * NN_ + (size_t)j * N_ + i0));
    }

    // ---- Compute 8 pixels (4 row-iterations x 2 adjacent columns) ----
#pragma unroll
    for (int s = 0; s < 4; ++s) {
        int j = jt + rr + 4 * s;
        float r2[2];
#pragma unroll
        for (int h = 0; h < 2; ++h) {
            int   i  = i0 + h;
            float vx = h ? pv[s].z : pv[s].x;
            float vy = h ? pv[s].w : pv[s].y;
            // fp32 op order must match numpy: ((i+0.5) - vx) + 3.5
            float px = ((float)i + 0.5f - vx) + 3.5f;
            float py = ((float)j + 0.5f - vy) + 3.5f;
            int x = (int)px;          // trunc toward zero == astype(int32)
            int y = (int)py;
            float fx = px - (float)x;
            float fy = py - (float)y;

            float g00, g01, g10, g11;
            // Fast path: all four taps (x..x+1, y..y+1) land in the grid
            // interior of the padded image -> no clip, no pad value.
            if ((unsigned)(x - BND_) <= (unsigned)(N_ - 2) &&
                (unsigned)(y - BND_) <= (unsigned)(N_ - 2)) {
                const float* p = gb + (y - BND_) * N_ + (x - BND_);
                g00 = p[0];
                g01 = p[1];
                g10 = p[N_];
                g11 = p[N_ + 1];
            } else {
                int idx = x + y * WP_;
                g00 = fetch_pad(gb, idx);
                g01 = fetch_pad(gb, idx + 1);
                g10 = fetch_pad(gb, idx + WP_);
                g11 = fetch_pad(gb, idx + WP_ + 1);
            }
            r2[h] = g00 * (1.0f - fx) * (1.0f - fy)
                  + g01 * fx          * (1.0f - fy)
                  + g10 * (1.0f - fx) * fy
                  + g11 * fx          * fy;
        }
        float2 st;
        st.x = r2[0];
        st.y = r2[1];
        *reinterpret_cast<float2*>(out + (size_t)b * NN_ + (size_t)j * N_ + i0) = st;
    }
}

extern "C" void kernel_launch(void* const* d_in, const int* in_sizes, int n_in,
                              void* d_out, int out_size, void* d_ws, size_t ws_size,
                              hipStream_t stream)
{
    const float* grid = (const float*)d_in[0];
    const float* vec  = (const float*)d_in[1];
    float* out = (float*)d_out;

    int total  = in_sizes[0];                     // B*N*N
    int nB     = total / NN_;                     // 16
    int blocks = nB * TILES_PER_IMG;              // 8192
    advect_kernel<<<blocks, 256, 0, stream>>>(grid, vec, out);
}

// Round 3
// 260.090 us; speedup vs baseline: 1.0233x; 1.0233x over previous
//
#include <hip/hip_runtime.h>
#include <stdint.h>

namespace {
constexpr int N_   = 1024;
constexpr int BND_ = 4;
constexpr int WP_  = N_ + 2 * BND_;   // 1032
constexpr int NN_  = N_ * N_;         // 1<<20

// 2-phase pipelined LDS version (T3 "minimum 2-phase" recipe).
// Each 256-thread block walks T_=8 vertical tiles of 128x16 pixels,
// double-buffering the staged grid window in LDS:
//   stage(buf^1, t+1)  ->  compute(t) from buf  ->  vmcnt(0)+barrier
// global_load_lds has no dest VGPR so hipcc emits NO automatic waits for
// it; the manual asm drain at phase end is the only wait, and it lands a
// full compute-phase (~2-3K cyc) after issue -> DMA latency hidden.
// R2 taught us scattered GLOBAL taps choke the L1 (each instr touches
// ~30-60 cache lines); scattered LDS taps cost ~6 cyc/instr instead.
constexpr int TW_ = 128;              // tile width
constexpr int TH_ = 16;               // tile height
constexpr int T_  = 8;                // tiles walked per block (128 rows)
constexpr int CW_ = 144;              // staged window cols = 36 float4/row
constexpr int CH_ = 32;               // staged window rows
constexpr int NV_ = (CW_ / 4) * CH_;  // 1152 16B chunks per window
constexpr int HALO_ = 8;
constexpr int GROUPS_Y = N_ / (TH_ * T_);            // 8
constexpr int TILES_PER_IMG = (N_ / TW_) * GROUPS_Y; // 64 blocks/image

// Exact replication of reference gather (rare fallback: border pixels /
// |v| beyond the staged halo): clip flat index into padded (WP x WP) sdf,
// then pad value 1.0 or interior grid value.
__device__ __forceinline__ float fetch_pad(const float* __restrict__ gb, int idx) {
    idx = min(max(idx, 0), WP_ * WP_ - 1);
    int yy = idx / WP_;
    int xx = idx - yy * WP_;
    if (xx >= BND_ && xx < WP_ - BND_ && yy >= BND_ && yy < WP_ - BND_)
        return gb[(yy - BND_) * N_ + (xx - BND_)];
    return 1.0f;
}

// Async global->LDS 16B copy (no VGPR round-trip, no dest register ->
// no compiler-inserted waits; we drain manually).
__device__ __forceinline__ void gload_lds16(const float* g, float* l) {
    __builtin_amdgcn_global_load_lds(
        (const __attribute__((address_space(1))) void*)(uintptr_t)g,
        (__attribute__((address_space(3))) void*)(uint32_t)(uintptr_t)l,
        16, 0, 0);
}

// Stage one 144x32 window. src0 = &grid[gj0*N + gi0] (16B-aligned:
// gi0 is a multiple of 4). 1152 chunks over 256 threads = 4.5/thread.
__device__ __forceinline__ void stage_tile(const float* src0, float* buf, int tid) {
#pragma unroll
    for (int u = 0; u < 5; ++u) {
        int e = tid + u * 256;
        if (u < 4 || e < NV_) {           // u<4 always in range; u==4: tid<128
            int r  = e / (CW_ / 4);
            int c4 = e - r * (CW_ / 4);
            gload_lds16(src0 + (size_t)r * N_ + 4 * c4, buf + 4 * e);
        }
    }
}

__device__ __forceinline__ void load_vec(float4* pv, const float* __restrict__ vec,
                                         size_t vb, int jt, int rr, int i0) {
#pragma unroll
    for (int s = 0; s < 4; ++s) {
        int j = jt + rr + 4 * s;
        pv[s] = *reinterpret_cast<const float4*>(vec + 2 * (vb + (size_t)j * N_ + i0));
    }
}
} // namespace

__global__ __launch_bounds__(256, 4) void advect_kernel(
    const float* __restrict__ grid,   // (B,N,N) fp32
    const float* __restrict__ vec,    // (B,N,N,2) fp32
    float* __restrict__ out)          // (B,N,N) fp32
{
    __shared__ float sg[2][CW_ * CH_];   // 2 x 18432 B

    int bid = blockIdx.x;
    int b   = bid >> 6;               // / TILES_PER_IMG (64)
    int r6  = bid & 63;
    int tyg = r6 >> 3;                // vertical group 0..7
    int txi = r6 & 7;
    int it  = txi * TW_;
    int jt0 = tyg * (TH_ * T_);       // first tile row of this block

    const float* gb = grid + (size_t)b * NN_;
    size_t vb = (size_t)b * NN_;
    int tid = threadIdx.x;
    int cp  = tid & 63;               // column-pair 0..63 (wave-contiguous)
    int rr  = tid >> 6;               // wave id 0..3 -> row offset
    int i0  = it + 2 * cp;

    // Window x-origin, clamped into the image (multiple of 4 -> 16B-aligned).
    int gi0 = min(max(it - HALO_, 0), N_ - CW_);

    // ---- Prologue: stage tile 0, load its vec ----
    {
        int gj0 = min(max(jt0 - HALO_, 0), N_ - CH_);
        stage_tile(gb + (size_t)gj0 * N_ + gi0, sg[0], tid);
    }
    float4 pv[4];
    load_vec(pv, vec, vb, jt0, rr, i0);
    asm volatile("s_waitcnt vmcnt(0)\n\ts_barrier" ::: "memory");

    // ---- Pipelined tile walk ----
#pragma unroll
    for (int t = 0; t < T_; ++t) {
        int jt  = jt0 + t * TH_;
        int gj0 = min(max(jt - HALO_, 0), N_ - CH_);

        float4 pvn[4];
        if (t + 1 < T_) {
            int jtn  = jt + TH_;
            int gj0n = min(max(jtn - HALO_, 0), N_ - CH_);
            stage_tile(gb + (size_t)gj0n * N_ + gi0, sg[(t + 1) & 1], tid);
            load_vec(pvn, vec, vb, jtn, rr, i0);
        }

        const float* sb = sg[t & 1];
#pragma unroll
        for (int s = 0; s < 4; ++s) {
            int j = jt + rr + 4 * s;
            float r2[2];
#pragma unroll
            for (int h = 0; h < 2; ++h) {
                int   i  = i0 + h;
                float vx = h ? pv[s].z : pv[s].x;
                float vy = h ? pv[s].w : pv[s].y;
                // fp32 op order must match numpy: ((i+0.5) - vx) + 3.5
                float px = ((float)i + 0.5f - vx) + 3.5f;
                float py = ((float)j + 0.5f - vy) + 3.5f;
                int x = (int)px;      // trunc toward zero == astype(int32)
                int y = (int)py;
                float fx = px - (float)x;
                float fy = py - (float)y;

                int lx = (x - BND_) - gi0;
                int ly = (y - BND_) - gj0;

                float g00, g01, g10, g11;
                if (lx >= 0 && lx <= CW_ - 2 && ly >= 0 && ly <= CH_ - 2) {
                    const float* p = &sb[ly * CW_ + lx];
                    g00 = p[0];
                    g01 = p[1];
                    g10 = p[CW_];
                    g11 = p[CW_ + 1];
                } else {
                    int idx = x + y * WP_;
                    g00 = fetch_pad(gb, idx);
                    g01 = fetch_pad(gb, idx + 1);
                    g10 = fetch_pad(gb, idx + WP_);
                    g11 = fetch_pad(gb, idx + WP_ + 1);
                }
                r2[h] = g00 * (1.0f - fx) * (1.0f - fy)
                      + g01 * fx          * (1.0f - fy)
                      + g10 * (1.0f - fx) * fy
                      + g11 * fx          * fy;
            }
            float2 st;
            st.x = r2[0];
            st.y = r2[1];
            *reinterpret_cast<float2*>(out + vb + (size_t)j * N_ + i0) = st;
        }

        // Drain tile t+1's DMAs (issued a full compute-phase ago) and
        // protect buf (t&1) before it is re-staged in iteration t+1.
        asm volatile("s_waitcnt vmcnt(0)\n\ts_barrier" ::: "memory");

        if (t + 1 < T_) {
#pragma unroll
            for (int q = 0; q < 4; ++q) pv[q] = pvn[q];
        }
    }
}

extern "C" void kernel_launch(void* const* d_in, const int* in_sizes, int n_in,
                              void* d_out, int out_size, void* d_ws, size_t ws_size,
                              hipStream_t stream)
{
    const float* grid = (const float*)d_in[0];
    const float* vec  = (const float*)d_in[1];
    float* out = (float*)d_out;

    int total  = in_sizes[0];                     // B*N*N
    int nB     = total / NN_;                     // 16
    int blocks = nB * TILES_PER_IMG;              // 1024
    advect_kernel<<<blocks, 256, 0, stream>>>(grid, vec, out);
}